// Round 21
// baseline (61.224 us; speedup 1.0000x reference)
//
#include <hip/hip_runtime.h>
#include <hip/hip_bf16.h>

#define S 512
#define HD 384
#define NPAIR 131328   // S*(S+1)/2
#define NOUT 14

typedef __bf16 bf16x8 __attribute__((ext_vector_type(8)));
typedef __bf16 bf16x4 __attribute__((ext_vector_type(4)));
typedef _Float16 f16x8 __attribute__((ext_vector_type(8)));
typedef float f32x4 __attribute__((ext_vector_type(4)));

__device__ __forceinline__ f32x4 splat4(float v) { return f32x4{v, v, v, v}; }
__device__ __forceinline__ f16x8 splat8h(float v) {
  _Float16 h = (_Float16)v;
  return f16x8{h, h, h, h, h, h, h, h};
}
__device__ __forceinline__ f16x8 cvt8h(f32x4 a, f32x4 b) {
  return f16x8{(_Float16)a[0], (_Float16)a[1], (_Float16)a[2], (_Float16)a[3],
               (_Float16)b[0], (_Float16)b[1], (_Float16)b[2], (_Float16)b[3]};
}

// tanh poly, deg-5 odd fit (same coeffs since R10). x already f16.
__device__ __forceinline__ f16x8 tanh8_from_x(f16x8 x) {
  f16x8 u = x * x;
  f16x8 p = __builtin_elementwise_fma(u, splat8h(0.065750f), splat8h(-0.303330f));
  p = __builtin_elementwise_fma(u, p, splat8h(0.997245f));
  return x * p;
}

// ---------- bf16 MFMA GEMM, BM=16 x BN=64, 4 waves, BK=128 ------------------
// B is staged TRANSPOSED from the raw f32 weight [K][Nsrc] (vector bf16x4
// writes), eliminating the separate transpose/prep launch. Same f32->bf16
// cast point and ascending k-order as the prep path -> bit-identical.
template<bool CVT_A, bool OUT_BF16, bool RELU, bool BIAS_LHALF, bool SPLIT_B>
__global__ __launch_bounds__(256) void gemm16t_kernel(
    const void* __restrict__ Ain, const float* __restrict__ Bsrc,
    int Nsrc, const float* __restrict__ bias, void* __restrict__ out,
    int K, int N)
{
  __shared__ __align__(16) __bf16 As[2][16][136];   //  8.7 KB
  __shared__ __align__(16) __bf16 Bs[2][64][136];   // 34.8 KB
  const int tid = threadIdx.x;
  const int m0 = blockIdx.y * 16, n0 = blockIdx.x * 64;
  const int lane = tid & 63, wave = tid >> 6;
  const int l15 = lane & 15, quad = lane >> 4, q8 = quad * 8;
  const int srA = tid >> 4, scA = (tid & 15) * 8;   // A: 16 rows x 16 thr x 8
  f32x4 acc = splat4(0.f);

  // B source (gemm3: Wcat = [cw_top | cw_bot], resolved per block)
  const float* Bs2 = Bsrc;
  int bn0 = n0;
  if (SPLIT_B && n0 >= HD) { Bs2 += (size_t)HD * HD; bn0 = n0 - HD; }
  const int kqB = tid >> 4, n4B = (tid & 15) * 4;   // this thread's B patch

  bf16x8 ra;
  f32x4 fb[8];
  auto loadA = [&](int ko) {
    if constexpr (CVT_A) {
      const float* Af = (const float*)Ain + (size_t)(m0 + srA) * K + scA + ko;
      f32x4 f0 = *(const f32x4*)(Af);
      f32x4 f1 = *(const f32x4*)(Af + 4);
      bf16x8 o;
      o[0] = (__bf16)f0[0]; o[1] = (__bf16)f0[1]; o[2] = (__bf16)f0[2]; o[3] = (__bf16)f0[3];
      o[4] = (__bf16)f1[0]; o[5] = (__bf16)f1[1]; o[6] = (__bf16)f1[2]; o[7] = (__bf16)f1[3];
      ra = o;
    } else {
      ra = *(const bf16x8*)((const __bf16*)Ain + (size_t)(m0 + srA) * K + scA + ko);
    }
  };
  // load 2 passes x 4 k-rows x float4-of-n  (coalesced: 16 lanes cover 64 n)
  auto loadB = [&](int ko) {
    #pragma unroll
    for (int p = 0; p < 2; ++p) {
      const int kl = kqB + p * 16;        // k-quad 0..31
      #pragma unroll
      for (int d = 0; d < 4; ++d)
        fb[p * 4 + d] = *(const f32x4*)(Bs2 + (size_t)(ko + kl * 4 + d) * Nsrc + bn0 + n4B);
    }
  };
  // transposed store: Bs[n][k], 4 x bf16x4 vector writes per pass
  auto storeB = [&](int buf) {
    #pragma unroll
    for (int p = 0; p < 2; ++p) {
      const int kl = kqB + p * 16;
      #pragma unroll
      for (int w = 0; w < 4; ++w) {
        bf16x4 v = {(__bf16)fb[p * 4 + 0][w], (__bf16)fb[p * 4 + 1][w],
                    (__bf16)fb[p * 4 + 2][w], (__bf16)fb[p * 4 + 3][w]};
        *(bf16x4*)&Bs[buf][n4B + w][kl * 4] = v;
      }
    }
  };
  loadA(0);
  loadB(0);

  const int nk = K >> 7;   // K multiple of 128
  int buf = 0;
  for (int it = 0; it < nk; ++it) {
    *(bf16x8*)&As[buf][srA][scA] = ra;
    storeB(buf);
    __syncthreads();
    if (it + 1 < nk) {
      const int ko = (it + 1) * 128;
      loadA(ko);
      loadB(ko);
    }
    #pragma unroll
    for (int s = 0; s < 4; ++s) {
      bf16x8 a = *(const bf16x8*)&As[buf][l15][s * 32 + q8];
      bf16x8 b = *(const bf16x8*)&Bs[buf][wave * 16 + l15][s * 32 + q8];
      acc = __builtin_amdgcn_mfma_f32_16x16x32_bf16(a, b, acc, 0, 0, 0);
    }
    buf ^= 1;
  }
  const int col = n0 + wave * 16 + l15;
  float bv = 0.f;
  if (BIAS_LHALF) { if (col < HD) bv = bias[col]; }
  else if (bias)  bv = bias[col];
  #pragma unroll
  for (int r = 0; r < 4; ++r) {
    int row = m0 + quad * 4 + r;
    float v = acc[r] + bv;
    if (RELU) v = fmaxf(v, 0.f);
    if (OUT_BF16) ((__bf16*)out)[(size_t)row * N + col] = (__bf16)v;
    else          ((float*)out)[(size_t)row * N + col] = v;
  }
}

// ---------- fused head: 16x16 tiles, 8 waves, f16 Rs + f16 poly/MFMA --------
// Rs staged as f16 (12 KB, halves R LDS traffic; LDS 25 KB -> 6 blocks/CU);
// Whead fragment-packed in-block from raw head weights (no prep dependency).
__global__ __launch_bounds__(512, 5) void fused_head_tile(
    const float* __restrict__ LR,
    const float* __restrict__ le_w, const float* __restrict__ le_b,
    const float* __restrict__ elh_w, const float* __restrict__ elh_b,
    const float* __restrict__ elt_w, const float* __restrict__ elt_b,
    const float* __restrict__ lgh_w, const float* __restrict__ lgh_b,
    const float* __restrict__ lgt_w, const float* __restrict__ lgt_b,
    float* __restrict__ out)
{
  __shared__ __align__(16) _Float16 Rsh[16][392];  // 12.5 KB, row 784B (16B-mult)
  __shared__ __align__(16) _Float16 Wl[6144];      // 12 KB fragment-packed Whead
  int x = blockIdx.x;
  int b = 0;
  if (x >= 528) { b = 1; x -= 528; }
  int ti = 0;
  while (x >= 32 - ti) { x -= 32 - ti; ++ti; }
  const int tj = ti + x;
  const int i0 = ti * 16, j0 = tj * 16;
  const int tid = threadIdx.x;

  const float* Rsrc = LR + (size_t)(b * S + j0) * (2 * HD) + HD;
  for (int t = tid; t < 768; t += 512) {           // 16 rows x 48 f16x8 chunks
    int row = t / 48, c8 = (t % 48) * 8;
    f32x4 v0 = *(const f32x4*)(Rsrc + (size_t)row * (2 * HD) + c8);
    f32x4 v1 = *(const f32x4*)(Rsrc + (size_t)row * (2 * HD) + c8 + 4);
    *(f16x8*)&Rsh[row][c8] = cvt8h(v0, v1);
  }
  if (tid < 384) {                                 // in-block Whead pack
    const int k = tid;
    float row[16];
    row[0] = le_w[k * 2 + 0];
    row[1] = le_w[k * 2 + 1];
    #pragma unroll
    for (int c = 0; c < 3; ++c) {
      row[2 + c]  = elh_w[k * 3 + c];
      row[5 + c]  = elt_w[k * 3 + c];
      row[8 + c]  = lgh_w[k * 3 + c];
      row[11 + c] = lgt_w[k * 3 + c];
    }
    row[14] = 0.f; row[15] = 0.f;
    int kk = k >> 5, qd = (k >> 3) & 3, e = k & 7;
    int base = ((kk * 4 + qd) * 16) * 8 + e;
    #pragma unroll
    for (int col = 0; col < 16; ++col)
      Wl[base + col * 8] = (_Float16)row[col];
  }
  const int lane = tid & 63, col = lane & 15, quad = lane >> 4;
  float bhv;
  {
    int c = col;
    bhv = (c < 2) ? le_b[c] : (c < 5) ? elh_b[c - 2] : (c < 8) ? elt_b[c - 5]
        : (c < 11) ? lgh_b[c - 8] : (c < 14) ? lgt_b[c - 11] : 0.f;
  }
  __syncthreads();

  const int wave = tid >> 6;            // 0..7; wave owns i-rows i, i+1
  const int i = i0 + wave * 2;
  const float* L0 = LR + (size_t)(b * S + i) * (2 * HD);
  const float* L1 = L0 + 2 * HD;
  f32x4 acc0 = splat4(0.f), acc1 = splat4(0.f);
  const int q8 = quad * 8;

  // depth-2 L (global) prefetch (proven R17/R18); R from f16 LDS (1 read/kk)
  f32x4 a0[2], a1[2], c0[2], c1[2];
  a0[0] = *(const f32x4*)(L0 + q8);       a1[0] = *(const f32x4*)(L0 + q8 + 4);
  c0[0] = *(const f32x4*)(L1 + q8);       c1[0] = *(const f32x4*)(L1 + q8 + 4);
  a0[1] = *(const f32x4*)(L0 + 32 + q8);  a1[1] = *(const f32x4*)(L0 + 32 + q8 + 4);
  c0[1] = *(const f32x4*)(L1 + 32 + q8);  c1[1] = *(const f32x4*)(L1 + 32 + q8 + 4);
  f16x8 r = *(const f16x8*)&Rsh[col][q8];

  #pragma unroll
  for (int kk = 0; kk < 12; ++kk) {
    const int p = kk & 1;                // compile-time per unrolled iter
    f32x4 ta0 = a0[p], ta1 = a1[p], tc0 = c0[p], tc1 = c1[p];
    if (kk < 10) {
      const int kb2 = (kk + 2) * 32 + q8;
      a0[p] = *(const f32x4*)(L0 + kb2); a1[p] = *(const f32x4*)(L0 + kb2 + 4);
      c0[p] = *(const f32x4*)(L1 + kb2); c1[p] = *(const f32x4*)(L1 + kb2 + 4);
    }
    f16x8 tr = r;
    if (kk < 11)
      r = *(const f16x8*)&Rsh[col][(kk + 1) * 32 + q8];
    f16x8 w = *(const f16x8*)&Wl[(size_t)((kk * 4 + quad) * 16 + col) * 8];
    f16x8 af = tanh8_from_x(cvt8h(ta0, ta1) + tr);
    acc0 = __builtin_amdgcn_mfma_f32_16x16x32_f16(af, w, acc0, 0, 0, 0);
    f16x8 ag = tanh8_from_x(cvt8h(tc0, tc1) + tr);
    acc1 = __builtin_amdgcn_mfma_f32_16x16x32_f16(ag, w, acc1, 0, 0, 0);
  }
  if (col < NOUT) {
    #pragma unroll
    for (int ii = 0; ii < 2; ++ii) {
      const int ic = i + ii;
      const f32x4 acc = ii ? acc1 : acc0;
      const size_t pbase = (size_t)b * NPAIR + (size_t)ic * S - ((size_t)ic * (ic - 1)) / 2;
      #pragma unroll
      for (int rr = 0; rr < 4; ++rr) {
        int j = j0 + quad * 4 + rr;
        if (j >= ic)
          out[(pbase + (size_t)(j - ic)) * NOUT + col] = acc[rr] + bhv;
      }
    }
  }
}

extern "C" void kernel_launch(void* const* d_in, const int* in_sizes, int n_in,
                              void* d_out, int out_size, void* d_ws, size_t ws_size,
                              hipStream_t stream) {
  const float* seq   = (const float*)d_in[0];
  const float* w1    = (const float*)d_in[1];
  const float* b1    = (const float*)d_in[2];
  const float* w2    = (const float*)d_in[3];
  const float* b2    = (const float*)d_in[4];
  const float* cw    = (const float*)d_in[5];
  const float* cbp   = (const float*)d_in[6];
  const float* le_w  = (const float*)d_in[7];
  const float* le_b  = (const float*)d_in[8];
  const float* elh_w = (const float*)d_in[9];
  const float* elh_b = (const float*)d_in[10];
  const float* elt_w = (const float*)d_in[11];
  const float* elt_b = (const float*)d_in[12];
  const float* lgh_w = (const float*)d_in[13];
  const float* lgh_b = (const float*)d_in[14];
  const float* lgt_w = (const float*)d_in[15];
  const float* lgt_b = (const float*)d_in[16];

  char* p = (char*)d_ws;
  float*  LRb = (float*)p;                   // 3,145,728 B  [L|R] f32, +cb on L
  __bf16* h1b = (__bf16*)(p + 1572864);      // overlaps LRb (dead before gemm3)
  __bf16* h2b = (__bf16*)(p + 3145728);      //   786,432 B  (total 3.93 MB)

  // 1) h1 = relu(seq @ w1 + b1) — B transposed in-staging from raw w1
  gemm16t_kernel<true, true, true, false, false><<<dim3(12, 64), 256, 0, stream>>>(
      seq, w1, 768, b1, h1b, 768, 768);
  // 2) h2 = relu(h1 @ w2 + b2) — from raw w2
  gemm16t_kernel<false, true, true, false, false><<<dim3(6, 64), 256, 0, stream>>>(
      h1b, w2, 384, b2, h2b, 768, 384);
  // 3) LR = h2 @ [w_top|w_bot] (+cb on L) — from raw cw, per-block half select
  gemm16t_kernel<false, false, false, true, true><<<dim3(12, 64), 256, 0, stream>>>(
      h2b, cw, 384, cbp, LRb, 384, 768);
  // 4) fused pair-head (Whead packed in-block)
  fused_head_tile<<<1056, 512, 0, stream>>>(
      LRb, le_w, le_b, elh_w, elh_b, elt_w, elt_b,
      lgh_w, lgh_b, lgt_w, lgt_b, (float*)d_out);
}

// Round 22
// 47.561 us; speedup vs baseline: 1.2873x; 1.2873x over previous
//
#include <hip/hip_runtime.h>
#include <hip/hip_bf16.h>

#define S 512
#define HD 384
#define NPAIR 131328   // S*(S+1)/2
#define NOUT 14

typedef __bf16 bf16x8 __attribute__((ext_vector_type(8)));
typedef _Float16 f16x8 __attribute__((ext_vector_type(8)));
typedef float f32x4 __attribute__((ext_vector_type(4)));

__device__ __forceinline__ f32x4 splat4(float v) { return f32x4{v, v, v, v}; }
__device__ __forceinline__ f16x8 splat8h(float v) {
  _Float16 h = (_Float16)v;
  return f16x8{h, h, h, h, h, h, h, h};
}

// tanh poly, deg-5 odd fit (same coeffs since R10). x already f16.
__device__ __forceinline__ f16x8 tanh8_from_x(f16x8 x) {
  f16x8 u = x * x;
  f16x8 p = __builtin_elementwise_fma(u, splat8h(0.065750f), splat8h(-0.303330f));
  p = __builtin_elementwise_fma(u, p, splat8h(0.997245f));
  return x * p;
}

// ---------- prep: weight transposes + head-weight fragment pack (R20) -------
__device__ __forceinline__ void transp_tile(
    const float* __restrict__ src, __bf16* __restrict__ dst,
    int R, int C, int bx, int by)
{
  __shared__ float t[32][33];
  const int tx = threadIdx.x & 31, ty = threadIdx.x >> 5;  // 32 x 8
  const int c = bx * 32 + tx;
  #pragma unroll
  for (int p = 0; p < 4; ++p) {
    int r = by * 32 + ty + p * 8;
    t[ty + p * 8][tx] = src[(size_t)r * C + c];
  }
  __syncthreads();
  #pragma unroll
  for (int p = 0; p < 4; ++p) {
    int cc = bx * 32 + ty + p * 8;
    int rr = by * 32 + tx;
    dst[(size_t)cc * R + rr] = (__bf16)t[tx][ty + p * 8];
  }
}

__global__ __launch_bounds__(256) void prep_all_kernel(
    const float* __restrict__ w1, __bf16* __restrict__ w1t,
    const float* __restrict__ w2, __bf16* __restrict__ w2t,
    const float* __restrict__ cw, __bf16* __restrict__ Wct,
    const float* __restrict__ le_w, const float* __restrict__ le_b,
    const float* __restrict__ elh_w, const float* __restrict__ elh_b,
    const float* __restrict__ elt_w, const float* __restrict__ elt_b,
    const float* __restrict__ lgh_w, const float* __restrict__ lgh_b,
    const float* __restrict__ lgt_w, const float* __restrict__ lgt_b,
    _Float16* __restrict__ Whb, float* __restrict__ bh)
{
  const int bid = blockIdx.x;
  if (bid < 576) {
    transp_tile(w1, w1t, 768, 768, bid % 24, bid / 24);
  } else if (bid < 864) {
    int idx = bid - 576;
    transp_tile(w2, w2t, 768, 384, idx % 12, idx / 12);
  } else if (bid < 1008) {
    int idx = bid - 864;
    transp_tile(cw, Wct, 384, 384, idx % 12, idx / 12);
  } else if (bid < 1152) {
    int idx = bid - 1008;
    transp_tile(cw + 384 * 384, Wct + (size_t)384 * 384, 384, 384, idx % 12, idx / 12);
  } else {
    for (int k = threadIdx.x; k < 384; k += 256) {
      float row[16];
      row[0] = le_w[k * 2 + 0];
      row[1] = le_w[k * 2 + 1];
      #pragma unroll
      for (int c = 0; c < 3; ++c) {
        row[2 + c]  = elh_w[k * 3 + c];
        row[5 + c]  = elt_w[k * 3 + c];
        row[8 + c]  = lgh_w[k * 3 + c];
        row[11 + c] = lgt_w[k * 3 + c];
      }
      row[14] = 0.f; row[15] = 0.f;
      int kk = k >> 5, quad = (k >> 3) & 3, e = k & 7;
      size_t base = (size_t)((kk * 4 + quad) * 16) * 8 + e;
      #pragma unroll
      for (int col = 0; col < 16; ++col)
        Whb[base + col * 8] = (_Float16)row[col];
      if (k < 16) {
        float v = 0.f;
        if (k < 2) v = le_b[k];
        else if (k < 5) v = elh_b[k - 2];
        else if (k < 8) v = elt_b[k - 5];
        else if (k < 11) v = lgh_b[k - 8];
        else if (k < 14) v = lgt_b[k - 11];
        bh[k] = v;
      }
    }
  }
}

// ---------- bf16 MFMA GEMM, BM=16 x BN=64, 4 waves, BK=128 (R18/R20) --------
// OMODE: 0 = f32 out, 1 = bf16 out, 2 = f16 out
template<bool CVT_A, int OMODE, bool RELU, bool BIAS_LHALF>
__global__ __launch_bounds__(256) void gemm16_kernel(
    const void* __restrict__ Ain, const __bf16* __restrict__ Wt,
    const float* __restrict__ bias, void* __restrict__ out,
    int K, int N)
{
  __shared__ __align__(16) __bf16 As[2][16][136];   //  8.7 KB
  __shared__ __align__(16) __bf16 Bs[2][64][136];   // 34.8 KB
  const int tid = threadIdx.x;
  const int m0 = blockIdx.y * 16, n0 = blockIdx.x * 64;
  const int lane = tid & 63, wave = tid >> 6;
  const int l15 = lane & 15, quad = lane >> 4, q8 = quad * 8;
  const int srA = tid >> 4, scA = (tid & 15) * 8;   // 16 rows x 16 thr x 8 bf16
  const int srB = tid >> 2, scB = (tid & 3) * 32;   // 64 rows x 4 thr x 32 bf16
  f32x4 acc = splat4(0.f);

  const __bf16* Bptr = Wt + (size_t)(n0 + srB) * K + scB;
  bf16x8 ra, rb0, rb1, rb2, rb3;
  auto loadA = [&](int ko) {
    if constexpr (CVT_A) {
      const float* Af = (const float*)Ain + (size_t)(m0 + srA) * K + scA + ko;
      float4 f0 = *(const float4*)(Af);
      float4 f1 = *(const float4*)(Af + 4);
      bf16x8 o;
      o[0] = (__bf16)f0.x; o[1] = (__bf16)f0.y; o[2] = (__bf16)f0.z; o[3] = (__bf16)f0.w;
      o[4] = (__bf16)f1.x; o[5] = (__bf16)f1.y; o[6] = (__bf16)f1.z; o[7] = (__bf16)f1.w;
      ra = o;
    } else {
      ra = *(const bf16x8*)((const __bf16*)Ain + (size_t)(m0 + srA) * K + scA + ko);
    }
  };
  auto loadB = [&](int ko) {
    rb0 = *(const bf16x8*)(Bptr + ko);
    rb1 = *(const bf16x8*)(Bptr + ko + 8);
    rb2 = *(const bf16x8*)(Bptr + ko + 16);
    rb3 = *(const bf16x8*)(Bptr + ko + 24);
  };
  loadA(0);
  loadB(0);

  const int nk = K >> 7;   // K multiple of 128
  int buf = 0;
  for (int it = 0; it < nk; ++it) {
    *(bf16x8*)&As[buf][srA][scA]      = ra;
    *(bf16x8*)&Bs[buf][srB][scB]      = rb0;
    *(bf16x8*)&Bs[buf][srB][scB + 8]  = rb1;
    *(bf16x8*)&Bs[buf][srB][scB + 16] = rb2;
    *(bf16x8*)&Bs[buf][srB][scB + 24] = rb3;
    __syncthreads();
    if (it + 1 < nk) {
      const int ko = (it + 1) * 128;
      loadA(ko);
      loadB(ko);
    }
    #pragma unroll
    for (int s = 0; s < 4; ++s) {
      bf16x8 a = *(const bf16x8*)&As[buf][l15][s * 32 + q8];
      bf16x8 b = *(const bf16x8*)&Bs[buf][wave * 16 + l15][s * 32 + q8];
      acc = __builtin_amdgcn_mfma_f32_16x16x32_bf16(a, b, acc, 0, 0, 0);
    }
    buf ^= 1;
  }
  const int col = n0 + wave * 16 + l15;
  float bv = 0.f;
  if (BIAS_LHALF) { if (col < HD) bv = bias[col]; }
  else if (bias)  bv = bias[col];
  #pragma unroll
  for (int r = 0; r < 4; ++r) {
    int row = m0 + quad * 4 + r;
    float v = acc[r] + bv;
    if (RELU) v = fmaxf(v, 0.f);
    if constexpr (OMODE == 1)      ((__bf16*)out)[(size_t)row * N + col] = (__bf16)v;
    else if constexpr (OMODE == 2) ((_Float16*)out)[(size_t)row * N + col] = (_Float16)v;
    else                           ((float*)out)[(size_t)row * N + col] = v;
  }
}

// ---------- fused head: 16x16 tiles, 8 waves, all-f16 datapath --------------
// LR now stored f16 by gemm3: L loads are f16x8 (no cvt), Rs staging is a
// pure 16B copy, adds/poly/MFMA all f16.
__global__ __launch_bounds__(512, 5) void fused_head_tile(
    const _Float16* __restrict__ LR, const _Float16* __restrict__ Whb,
    const float* __restrict__ bh, float* __restrict__ out)
{
  __shared__ __align__(16) _Float16 Rsh[16][392];  // 12.5 KB
  __shared__ __align__(16) _Float16 Wl[6144];      // 12 KB
  int x = blockIdx.x;
  int b = 0;
  if (x >= 528) { b = 1; x -= 528; }
  int ti = 0;
  while (x >= 32 - ti) { x -= 32 - ti; ++ti; }
  const int tj = ti + x;
  const int i0 = ti * 16, j0 = tj * 16;
  const int tid = threadIdx.x;

  const _Float16* Rsrc = LR + (size_t)(b * S + j0) * (2 * HD) + HD;
  for (int t = tid; t < 768; t += 512) {           // 16 rows x 48 f16x8 chunks
    int row = t / 48, c8 = (t % 48) * 8;
    *(f16x8*)&Rsh[row][c8] = *(const f16x8*)(Rsrc + (size_t)row * (2 * HD) + c8);
  }
  for (int t = tid; t < 768; t += 512)
    ((f16x8*)Wl)[t] = ((const f16x8*)Whb)[t];
  const int lane = tid & 63, col = lane & 15, quad = lane >> 4;
  const float bhv = bh[col];
  __syncthreads();

  const int wave = tid >> 6;            // 0..7; wave owns i-rows i, i+1
  const int i = i0 + wave * 2;
  const _Float16* L0 = LR + (size_t)(b * S + i) * (2 * HD);
  const _Float16* L1 = L0 + 2 * HD;
  f32x4 acc0 = splat4(0.f), acc1 = splat4(0.f);
  const int q8 = quad * 8;

  // depth-2 L (global) prefetch (structure proven R17/R18), f16x8 regs
  f16x8 a[2], c[2];
  a[0] = *(const f16x8*)(L0 + q8);
  c[0] = *(const f16x8*)(L1 + q8);
  a[1] = *(const f16x8*)(L0 + 32 + q8);
  c[1] = *(const f16x8*)(L1 + 32 + q8);
  f16x8 r = *(const f16x8*)&Rsh[col][q8];

  #pragma unroll
  for (int kk = 0; kk < 12; ++kk) {
    const int p = kk & 1;                // compile-time per unrolled iter
    f16x8 ta = a[p], tc = c[p];
    if (kk < 10) {
      const int kb2 = (kk + 2) * 32 + q8;
      a[p] = *(const f16x8*)(L0 + kb2);
      c[p] = *(const f16x8*)(L1 + kb2);
    }
    f16x8 tr = r;
    if (kk < 11)
      r = *(const f16x8*)&Rsh[col][(kk + 1) * 32 + q8];
    f16x8 w = *(const f16x8*)&Wl[(size_t)((kk * 4 + quad) * 16 + col) * 8];
    f16x8 af = tanh8_from_x(ta + tr);
    acc0 = __builtin_amdgcn_mfma_f32_16x16x32_f16(af, w, acc0, 0, 0, 0);
    f16x8 ag = tanh8_from_x(tc + tr);
    acc1 = __builtin_amdgcn_mfma_f32_16x16x32_f16(ag, w, acc1, 0, 0, 0);
  }
  if (col < NOUT) {
    #pragma unroll
    for (int ii = 0; ii < 2; ++ii) {
      const int ic = i + ii;
      const f32x4 acc = ii ? acc1 : acc0;
      const size_t pbase = (size_t)b * NPAIR + (size_t)ic * S - ((size_t)ic * (ic - 1)) / 2;
      #pragma unroll
      for (int rr = 0; rr < 4; ++rr) {
        int j = j0 + quad * 4 + rr;
        if (j >= ic)
          out[(pbase + (size_t)(j - ic)) * NOUT + col] = acc[rr] + bhv;
      }
    }
  }
}

extern "C" void kernel_launch(void* const* d_in, const int* in_sizes, int n_in,
                              void* d_out, int out_size, void* d_ws, size_t ws_size,
                              hipStream_t stream) {
  const float* seq   = (const float*)d_in[0];
  const float* w1    = (const float*)d_in[1];
  const float* b1    = (const float*)d_in[2];
  const float* w2    = (const float*)d_in[3];
  const float* b2    = (const float*)d_in[4];
  const float* cw    = (const float*)d_in[5];
  const float* cbp   = (const float*)d_in[6];
  const float* le_w  = (const float*)d_in[7];
  const float* le_b  = (const float*)d_in[8];
  const float* elh_w = (const float*)d_in[9];
  const float* elh_b = (const float*)d_in[10];
  const float* elt_w = (const float*)d_in[11];
  const float* elt_b = (const float*)d_in[12];
  const float* lgh_w = (const float*)d_in[13];
  const float* lgh_b = (const float*)d_in[14];
  const float* lgt_w = (const float*)d_in[15];
  const float* lgt_b = (const float*)d_in[16];

  char* p = (char*)d_ws;
  _Float16* LRb = (_Float16*)p;              // 1,572,864 B  [L|R] f16, +cb on L
  __bf16*   h1b = (__bf16*)(p + 1572864);    // 1,572,864 B
  __bf16*   h2b = (__bf16*)(p + 3145728);    //   786,432 B
  __bf16*   w1t = (__bf16*)(p + 3932160);    // 1,179,648 B
  __bf16*   w2t = (__bf16*)(p + 5111808);    //   589,824 B
  __bf16*   Wct = (__bf16*)(p + 5701632);    //   589,824 B
  float*    bh  = (float*)(p + 6291456);     //        64 B
  _Float16* Whb = (_Float16*)(p + 6291520);  //    12,288 B

  prep_all_kernel<<<1153, 256, 0, stream>>>(
      w1, w1t, w2, w2t, cw, Wct,
      le_w, le_b, elh_w, elh_b, elt_w, elt_b,
      lgh_w, lgh_b, lgt_w, lgt_b, Whb, bh);
  // h1 = relu(seq @ w1 + b1); 768 blocks
  gemm16_kernel<true, 1, true, false><<<dim3(12, 64), 256, 0, stream>>>(
      seq, w1t, b1, h1b, 768, 768);
  // h2 = relu(h1 @ w2 + b2); 384 blocks
  gemm16_kernel<false, 1, true, false><<<dim3(6, 64), 256, 0, stream>>>(
      h1b, w2t, b2, h2b, 768, 384);
  // LR = h2 @ [w_top|w_bot] (+cb on L), f16 out; 768 blocks
  gemm16_kernel<false, 2, false, true><<<dim3(12, 64), 256, 0, stream>>>(
      h2b, Wct, cbp, LRb, 384, 768);
  fused_head_tile<<<1056, 512, 0, stream>>>(LRb, Whb, bh, (float*)d_out);
}

// Round 23
// 47.441 us; speedup vs baseline: 1.2905x; 1.0025x over previous
//
#include <hip/hip_runtime.h>
#include <hip/hip_bf16.h>

#define S 512
#define HD 384
#define NPAIR 131328   // S*(S+1)/2
#define NOUT 14

typedef __bf16 bf16x8 __attribute__((ext_vector_type(8)));
typedef _Float16 f16x8 __attribute__((ext_vector_type(8)));
typedef float f32x4 __attribute__((ext_vector_type(4)));

__device__ __forceinline__ f32x4 splat4(float v) { return f32x4{v, v, v, v}; }
__device__ __forceinline__ f16x8 splat8h(float v) {
  _Float16 h = (_Float16)v;
  return f16x8{h, h, h, h, h, h, h, h};
}

// tanh poly, deg-5 odd fit (same coeffs since R10). x already f16.
__device__ __forceinline__ f16x8 tanh8_from_x(f16x8 x) {
  f16x8 u = x * x;
  f16x8 p = __builtin_elementwise_fma(u, splat8h(0.065750f), splat8h(-0.303330f));
  p = __builtin_elementwise_fma(u, p, splat8h(0.997245f));
  return x * p;
}

// ---------- prep: weight transposes + head-weight fragment pack (R20) -------
__device__ __forceinline__ void transp_tile(
    const float* __restrict__ src, __bf16* __restrict__ dst,
    int R, int C, int bx, int by)
{
  __shared__ float t[32][33];
  const int tx = threadIdx.x & 31, ty = threadIdx.x >> 5;  // 32 x 8
  const int c = bx * 32 + tx;
  #pragma unroll
  for (int p = 0; p < 4; ++p) {
    int r = by * 32 + ty + p * 8;
    t[ty + p * 8][tx] = src[(size_t)r * C + c];
  }
  __syncthreads();
  #pragma unroll
  for (int p = 0; p < 4; ++p) {
    int cc = bx * 32 + ty + p * 8;
    int rr = by * 32 + tx;
    dst[(size_t)cc * R + rr] = (__bf16)t[tx][ty + p * 8];
  }
}

__global__ __launch_bounds__(256) void prep_all_kernel(
    const float* __restrict__ w1, __bf16* __restrict__ w1t,
    const float* __restrict__ w2, __bf16* __restrict__ w2t,
    const float* __restrict__ cw, __bf16* __restrict__ Wct,
    const float* __restrict__ le_w, const float* __restrict__ le_b,
    const float* __restrict__ elh_w, const float* __restrict__ elh_b,
    const float* __restrict__ elt_w, const float* __restrict__ elt_b,
    const float* __restrict__ lgh_w, const float* __restrict__ lgh_b,
    const float* __restrict__ lgt_w, const float* __restrict__ lgt_b,
    _Float16* __restrict__ Whb, float* __restrict__ bh)
{
  const int bid = blockIdx.x;
  if (bid < 576) {
    transp_tile(w1, w1t, 768, 768, bid % 24, bid / 24);
  } else if (bid < 864) {
    int idx = bid - 576;
    transp_tile(w2, w2t, 768, 384, idx % 12, idx / 12);
  } else if (bid < 1008) {
    int idx = bid - 864;
    transp_tile(cw, Wct, 384, 384, idx % 12, idx / 12);
  } else if (bid < 1152) {
    int idx = bid - 1008;
    transp_tile(cw + 384 * 384, Wct + (size_t)384 * 384, 384, 384, idx % 12, idx / 12);
  } else {
    for (int k = threadIdx.x; k < 384; k += 256) {
      float row[16];
      row[0] = le_w[k * 2 + 0];
      row[1] = le_w[k * 2 + 1];
      #pragma unroll
      for (int c = 0; c < 3; ++c) {
        row[2 + c]  = elh_w[k * 3 + c];
        row[5 + c]  = elt_w[k * 3 + c];
        row[8 + c]  = lgh_w[k * 3 + c];
        row[11 + c] = lgt_w[k * 3 + c];
      }
      row[14] = 0.f; row[15] = 0.f;
      int kk = k >> 5, quad = (k >> 3) & 3, e = k & 7;
      size_t base = (size_t)((kk * 4 + quad) * 16) * 8 + e;
      #pragma unroll
      for (int col = 0; col < 16; ++col)
        Whb[base + col * 8] = (_Float16)row[col];
      if (k < 16) {
        float v = 0.f;
        if (k < 2) v = le_b[k];
        else if (k < 5) v = elh_b[k - 2];
        else if (k < 8) v = elt_b[k - 5];
        else if (k < 11) v = lgh_b[k - 8];
        else if (k < 14) v = lgt_b[k - 11];
        bh[k] = v;
      }
    }
  }
}

// ---------- bf16 MFMA GEMM, BM=16 x BN=64, 4 waves, BK=128 (R18/R20) --------
// OMODE: 0 = f32 out, 1 = bf16 out, 2 = f16 out
template<bool CVT_A, int OMODE, bool RELU, bool BIAS_LHALF>
__global__ __launch_bounds__(256) void gemm16_kernel(
    const void* __restrict__ Ain, const __bf16* __restrict__ Wt,
    const float* __restrict__ bias, void* __restrict__ out,
    int K, int N)
{
  __shared__ __align__(16) __bf16 As[2][16][136];   //  8.7 KB
  __shared__ __align__(16) __bf16 Bs[2][64][136];   // 34.8 KB
  const int tid = threadIdx.x;
  const int m0 = blockIdx.y * 16, n0 = blockIdx.x * 64;
  const int lane = tid & 63, wave = tid >> 6;
  const int l15 = lane & 15, quad = lane >> 4, q8 = quad * 8;
  const int srA = tid >> 4, scA = (tid & 15) * 8;   // 16 rows x 16 thr x 8 bf16
  const int srB = tid >> 2, scB = (tid & 3) * 32;   // 64 rows x 4 thr x 32 bf16
  f32x4 acc = splat4(0.f);

  const __bf16* Bptr = Wt + (size_t)(n0 + srB) * K + scB;
  bf16x8 ra, rb0, rb1, rb2, rb3;
  auto loadA = [&](int ko) {
    if constexpr (CVT_A) {
      const float* Af = (const float*)Ain + (size_t)(m0 + srA) * K + scA + ko;
      float4 f0 = *(const float4*)(Af);
      float4 f1 = *(const float4*)(Af + 4);
      bf16x8 o;
      o[0] = (__bf16)f0.x; o[1] = (__bf16)f0.y; o[2] = (__bf16)f0.z; o[3] = (__bf16)f0.w;
      o[4] = (__bf16)f1.x; o[5] = (__bf16)f1.y; o[6] = (__bf16)f1.z; o[7] = (__bf16)f1.w;
      ra = o;
    } else {
      ra = *(const bf16x8*)((const __bf16*)Ain + (size_t)(m0 + srA) * K + scA + ko);
    }
  };
  auto loadB = [&](int ko) {
    rb0 = *(const bf16x8*)(Bptr + ko);
    rb1 = *(const bf16x8*)(Bptr + ko + 8);
    rb2 = *(const bf16x8*)(Bptr + ko + 16);
    rb3 = *(const bf16x8*)(Bptr + ko + 24);
  };
  loadA(0);
  loadB(0);

  const int nk = K >> 7;   // K multiple of 128
  int buf = 0;
  for (int it = 0; it < nk; ++it) {
    *(bf16x8*)&As[buf][srA][scA]      = ra;
    *(bf16x8*)&Bs[buf][srB][scB]      = rb0;
    *(bf16x8*)&Bs[buf][srB][scB + 8]  = rb1;
    *(bf16x8*)&Bs[buf][srB][scB + 16] = rb2;
    *(bf16x8*)&Bs[buf][srB][scB + 24] = rb3;
    __syncthreads();
    if (it + 1 < nk) {
      const int ko = (it + 1) * 128;
      loadA(ko);
      loadB(ko);
    }
    #pragma unroll
    for (int s = 0; s < 4; ++s) {
      bf16x8 a = *(const bf16x8*)&As[buf][l15][s * 32 + q8];
      bf16x8 b = *(const bf16x8*)&Bs[buf][wave * 16 + l15][s * 32 + q8];
      acc = __builtin_amdgcn_mfma_f32_16x16x32_bf16(a, b, acc, 0, 0, 0);
    }
    buf ^= 1;
  }
  const int col = n0 + wave * 16 + l15;
  float bv = 0.f;
  if (BIAS_LHALF) { if (col < HD) bv = bias[col]; }
  else if (bias)  bv = bias[col];
  #pragma unroll
  for (int r = 0; r < 4; ++r) {
    int row = m0 + quad * 4 + r;
    float v = acc[r] + bv;
    if (RELU) v = fmaxf(v, 0.f);
    if constexpr (OMODE == 1)      ((__bf16*)out)[(size_t)row * N + col] = (__bf16)v;
    else if constexpr (OMODE == 2) ((_Float16*)out)[(size_t)row * N + col] = (_Float16)v;
    else                           ((float*)out)[(size_t)row * N + col] = v;
  }
}

// ---------- fused head: all-f16 datapath, 32 waves/CU target ----------------
// launch_bounds(512,8) caps VGPR at 64 -> 8 waves/SIMD residency; depth-1 L
// prefetch (R17: depth-2 == depth-1) to keep register demand under the cap.
__global__ __launch_bounds__(512, 8) void fused_head_tile(
    const _Float16* __restrict__ LR, const _Float16* __restrict__ Whb,
    const float* __restrict__ bh, float* __restrict__ out)
{
  __shared__ __align__(16) _Float16 Rsh[16][392];  // 12.5 KB
  __shared__ __align__(16) _Float16 Wl[6144];      // 12 KB
  int x = blockIdx.x;
  int b = 0;
  if (x >= 528) { b = 1; x -= 528; }
  int ti = 0;
  while (x >= 32 - ti) { x -= 32 - ti; ++ti; }
  const int tj = ti + x;
  const int i0 = ti * 16, j0 = tj * 16;
  const int tid = threadIdx.x;

  const _Float16* Rsrc = LR + (size_t)(b * S + j0) * (2 * HD) + HD;
  for (int t = tid; t < 768; t += 512) {           // 16 rows x 48 f16x8 chunks
    int row = t / 48, c8 = (t % 48) * 8;
    *(f16x8*)&Rsh[row][c8] = *(const f16x8*)(Rsrc + (size_t)row * (2 * HD) + c8);
  }
  for (int t = tid; t < 768; t += 512)
    ((f16x8*)Wl)[t] = ((const f16x8*)Whb)[t];
  const int lane = tid & 63, col = lane & 15, quad = lane >> 4;
  const float bhv = bh[col];
  __syncthreads();

  const int wave = tid >> 6;            // 0..7; wave owns i-rows i, i+1
  const int i = i0 + wave * 2;
  const _Float16* L0 = LR + (size_t)(b * S + i) * (2 * HD);
  const _Float16* L1 = L0 + 2 * HD;
  f32x4 acc0 = splat4(0.f), acc1 = splat4(0.f);
  const int q8 = quad * 8;

  // depth-1 prefetch on L (global) and R (LDS)
  f16x8 a = *(const f16x8*)(L0 + q8);
  f16x8 c = *(const f16x8*)(L1 + q8);
  f16x8 r = *(const f16x8*)&Rsh[col][q8];

  #pragma unroll
  for (int kk = 0; kk < 12; ++kk) {
    f16x8 na, nc, nr;
    if (kk < 11) {
      const int kb1 = (kk + 1) * 32 + q8;
      na = *(const f16x8*)(L0 + kb1);
      nc = *(const f16x8*)(L1 + kb1);
      nr = *(const f16x8*)&Rsh[col][kb1];
    }
    f16x8 w = *(const f16x8*)&Wl[(size_t)((kk * 4 + quad) * 16 + col) * 8];
    f16x8 af = tanh8_from_x(a + r);
    acc0 = __builtin_amdgcn_mfma_f32_16x16x32_f16(af, w, acc0, 0, 0, 0);
    f16x8 ag = tanh8_from_x(c + r);
    acc1 = __builtin_amdgcn_mfma_f32_16x16x32_f16(ag, w, acc1, 0, 0, 0);
    a = na; c = nc; r = nr;
  }
  if (col < NOUT) {
    #pragma unroll
    for (int ii = 0; ii < 2; ++ii) {
      const int ic = i + ii;
      const f32x4 acc = ii ? acc1 : acc0;
      const size_t pbase = (size_t)b * NPAIR + (size_t)ic * S - ((size_t)ic * (ic - 1)) / 2;
      #pragma unroll
      for (int rr = 0; rr < 4; ++rr) {
        int j = j0 + quad * 4 + rr;
        if (j >= ic)
          out[(pbase + (size_t)(j - ic)) * NOUT + col] = acc[rr] + bhv;
      }
    }
  }
}

extern "C" void kernel_launch(void* const* d_in, const int* in_sizes, int n_in,
                              void* d_out, int out_size, void* d_ws, size_t ws_size,
                              hipStream_t stream) {
  const float* seq   = (const float*)d_in[0];
  const float* w1    = (const float*)d_in[1];
  const float* b1    = (const float*)d_in[2];
  const float* w2    = (const float*)d_in[3];
  const float* b2    = (const float*)d_in[4];
  const float* cw    = (const float*)d_in[5];
  const float* cbp   = (const float*)d_in[6];
  const float* le_w  = (const float*)d_in[7];
  const float* le_b  = (const float*)d_in[8];
  const float* elh_w = (const float*)d_in[9];
  const float* elh_b = (const float*)d_in[10];
  const float* elt_w = (const float*)d_in[11];
  const float* elt_b = (const float*)d_in[12];
  const float* lgh_w = (const float*)d_in[13];
  const float* lgh_b = (const float*)d_in[14];
  const float* lgt_w = (const float*)d_in[15];
  const float* lgt_b = (const float*)d_in[16];

  char* p = (char*)d_ws;
  _Float16* LRb = (_Float16*)p;              // 1,572,864 B  [L|R] f16, +cb on L
  __bf16*   h1b = (__bf16*)(p + 1572864);    // 1,572,864 B
  __bf16*   h2b = (__bf16*)(p + 3145728);    //   786,432 B
  __bf16*   w1t = (__bf16*)(p + 3932160);    // 1,179,648 B
  __bf16*   w2t = (__bf16*)(p + 5111808);    //   589,824 B
  __bf16*   Wct = (__bf16*)(p + 5701632);    //   589,824 B
  float*    bh  = (float*)(p + 6291456);     //        64 B
  _Float16* Whb = (_Float16*)(p + 6291520);  //    12,288 B

  prep_all_kernel<<<1153, 256, 0, stream>>>(
      w1, w1t, w2, w2t, cw, Wct,
      le_w, le_b, elh_w, elh_b, elt_w, elt_b,
      lgh_w, lgh_b, lgt_w, lgt_b, Whb, bh);
  // h1 = relu(seq @ w1 + b1); 768 blocks
  gemm16_kernel<true, 1, true, false><<<dim3(12, 64), 256, 0, stream>>>(
      seq, w1t, b1, h1b, 768, 768);
  // h2 = relu(h1 @ w2 + b2); 384 blocks
  gemm16_kernel<false, 1, true, false><<<dim3(6, 64), 256, 0, stream>>>(
      h1b, w2t, b2, h2b, 768, 384);
  // LR = h2 @ [w_top|w_bot] (+cb on L), f16 out; 768 blocks
  gemm16_kernel<false, 2, false, true><<<dim3(12, 64), 256, 0, stream>>>(
      h2b, Wct, cbp, LRb, 384, 768);
  fused_head_tile<<<1056, 512, 0, stream>>>(LRb, Whb, bh, (float*)d_out);
}